// Round 3
// baseline (1124.607 us; speedup 1.0000x reference)
//
#include <hip/hip_runtime.h>
#include <hip/hip_bf16.h>

#define NN 50000
#define NE 400000
#define AVG_LOG_F 2.1972245773362196f
#define EPSV 1e-5f

typedef __hip_bfloat16 bf16;
typedef __attribute__((ext_vector_type(8))) short short8v;
typedef __attribute__((ext_vector_type(4))) float f32x4;

__device__ __forceinline__ float b2f(bf16 v){ return __bfloat162float(v); }
__device__ __forceinline__ bf16  f2b(float v){ return __float2bfloat16(v); }
__device__ __forceinline__ short f2s(float v){
  bf16 b = __float2bfloat16(v);
  short s; __builtin_memcpy(&s, &b, 2); return s;
}

// ---------- h0[n][d] = sum_c atom_emb[c][x[n][c]][d] ----------
__global__ void k_h0(const int* __restrict__ x, const float* __restrict__ aemb,
                     float* __restrict__ h0){
  int idx = blockIdx.x * 256 + threadIdx.x;
  if (idx >= NN * 64) return;
  int n = idx >> 6, d = idx & 63;
  float acc = 0.f;
  #pragma unroll
  for (int c = 0; c < 9; ++c){
    int a = x[n * 9 + c];
    acc += aemb[(c * 64 + a) * 64 + d];
  }
  h0[idx] = acc;
}

// ---------- degree histogram + bond code ----------
__global__ void k_deg_code(const int* __restrict__ ei, const int* __restrict__ ea,
                           int* __restrict__ deg, int* __restrict__ code){
  int e = blockIdx.x * 256 + threadIdx.x;
  if (e >= NE) return;
  int dst = ei[NE + e];
  atomicAdd(&deg[dst], 1);
  code[e] = ea[e * 3] + 8 * ea[e * 3 + 1] + 64 * ea[e * 3 + 2];
}

// ---------- exclusive scan of deg -> rowptr ----------
__global__ void k_scan1(const int* __restrict__ deg, int* __restrict__ rowptr,
                        int* __restrict__ part){
  __shared__ int s[256];
  int t = threadIdx.x, i = blockIdx.x * 256 + t;
  int v = (i < NN) ? deg[i] : 0;
  s[t] = v; __syncthreads();
  for (int off = 1; off < 256; off <<= 1){
    int xv = (t >= off) ? s[t - off] : 0;
    __syncthreads();
    s[t] += xv;
    __syncthreads();
  }
  if (i < NN) rowptr[i] = s[t] - v;
  if (t == 255) part[blockIdx.x] = s[255];
}

__global__ void k_scan2(int* __restrict__ part, int nblk){
  __shared__ int s[256];
  int t = threadIdx.x;
  int v = (t < nblk) ? part[t] : 0;
  s[t] = v; __syncthreads();
  for (int off = 1; off < 256; off <<= 1){
    int xv = (t >= off) ? s[t - off] : 0;
    __syncthreads();
    s[t] += xv;
    __syncthreads();
  }
  if (t < nblk) part[t] = s[t] - v;
}

__global__ void k_scan3(int* __restrict__ rowptr, const int* __restrict__ part,
                        const int* __restrict__ deg, float* __restrict__ amp,
                        float* __restrict__ att){
  int i = blockIdx.x * 256 + threadIdx.x;
  if (i < NN){
    rowptr[i] += part[blockIdx.x];
    int d = deg[i];
    float ld = logf((float)max(d, 1) + 1.0f);
    amp[i] = ld / AVG_LOG_F;
    att[i] = AVG_LOG_F / ld;
  }
  if (i == 0) rowptr[NN] = NE;
}

// ---------- scatter edges into CSR order ----------
__global__ void k_scatter(const int* __restrict__ ei, const int* __restrict__ code,
                          const int* __restrict__ rowptr, int* __restrict__ cursor,
                          int* __restrict__ ssrc, int* __restrict__ scode){
  int e = blockIdx.x * 256 + threadIdx.x;
  if (e >= NE) return;
  int dst = ei[NE + e];
  int pos = rowptr[dst] + atomicAdd(&cursor[dst], 1);
  ssrc[pos]  = ei[e];
  scode[pos] = code[e];
}

// ---------- ctab[code][l][d] = (sum_c bond_emb[c][attr_c]) @ preW_e[l] ----------
__global__ void k_ctab(const float* __restrict__ bemb, const float* __restrict__ preW,
                       bf16* __restrict__ ctab){
  __shared__ float et[64];
  int cb = blockIdx.x, l = blockIdx.y, t = threadIdx.x;
  int a0 = cb & 7, a1 = (cb >> 3) & 7, a2 = (cb >> 6) & 7;
  et[t] = bemb[(0 * 8 + a0) * 64 + t] + bemb[(1 * 8 + a1) * 64 + t] + bemb[(2 * 8 + a2) * 64 + t];
  __syncthreads();
  float acc = 0.f;
  const float* W = preW + (l * 192 + 128) * 64;
  for (int k = 0; k < 64; ++k) acc += et[k] * W[k * 64 + t];
  ctab[(cb * 5 + l) * 64 + t] = f2b(acc);
}

// ---------- Whsum / bias sums ----------
__global__ void k_whsum(const float* __restrict__ postW, const float* __restrict__ postb,
                        float* __restrict__ whs, float* __restrict__ bs){
  int idx = blockIdx.x * 256 + threadIdx.x;
  if (idx < 4096){
    int k = idx >> 6, d = idx & 63;
    float a = 0.f;
    for (int l = 0; l < 5; ++l) a += postW[(size_t)(l * 832 + 768 + k) * 64 + d];
    whs[idx] = a;
  }
  if (idx < 64){
    float a = 0.f;
    for (int l = 0; l < 5; ++l) a += postb[l * 64 + idx];
    bs[idx] = a;
  }
}

// ---------- Wt[l][cc][k] = postW[l][g*256 + k][c], cc=g*64+c (fragment-ready bf16) ----------
__global__ void k_wt(const float* __restrict__ postW, bf16* __restrict__ Wt){
  int idx = blockIdx.x * 256 + threadIdx.x;
  if (idx >= 5 * 192 * 256) return;
  int l = idx / (192 * 256);
  int rem = idx % (192 * 256);
  int cc = rem >> 8;
  int k  = rem & 255;
  int g = cc >> 6, c = cc & 63;
  Wt[idx] = f2b(postW[((size_t)l * 832 + g * 256 + k) * 64 + c]);
}

// ---------- Wtp[gc][k] = preW block col-transposed (bf16) + bias640 ----------
// gc = s*64 + c; s<5: W_dst layer s (bias=preb), s>=5: W_src layer s-5 (bias=0)
__global__ void k_wtpre(const float* __restrict__ preW, const float* __restrict__ preb,
                        bf16* __restrict__ Wtp, float* __restrict__ bias640){
  int idx = blockIdx.x * 256 + threadIdx.x;
  if (idx < 640 * 64){
    int gc = idx >> 6, k = idx & 63;
    int s = gc >> 6, c = gc & 63;
    int l = (s < 5) ? s : s - 5;
    int off = (s < 5) ? 0 : 64;
    Wtp[idx] = f2b(preW[(size_t)(l * 192 + off + k) * 64 + c]);
  }
  if (idx < 640){
    int s = idx >> 6, c = idx & 63;
    bias640[idx] = (s < 5) ? preb[s * 64 + c] : 0.f;
  }
}

// ---------- AB = h0[N,64] @ Wcat[64,640] via MFMA; AB[n][s][64] bf16 ----------
// grid (ceil(N/128), 4): 128 rows x 160 cols per block; 4 waves x (32 rows x 160 cols)
__global__ __launch_bounds__(256) void k_ab_mfma(const float* __restrict__ h0,
                                                 const bf16* __restrict__ Wtp,
                                                 const float* __restrict__ bias640,
                                                 bf16* __restrict__ AB){
  __shared__ bf16 As[128][72];   // rows x K=64 (+8 pad)
  __shared__ bf16 Bs[160][72];   // cols x K=64 (+8 pad)
  const int t = threadIdx.x;
  const int n0 = blockIdx.x * 128;
  const int gc0 = blockIdx.y * 160;
  const int lane = t & 63, wid = t >> 6;
  const int rw = wid * 32;
  const short* Wp = (const short*)Wtp;

  // stage A: h0 f32 -> bf16
  {
    int r = t >> 1, h = t & 1;
    int n = n0 + r;
    #pragma unroll
    for (int q = 0; q < 4; ++q){
      short8v v;
      if (n < NN){
        const float* src = h0 + (size_t)n * 64 + h * 32 + q * 8;
        float4 fa = *(const float4*)src;
        float4 fb = *(const float4*)(src + 4);
        v[0]=f2s(fa.x); v[1]=f2s(fa.y); v[2]=f2s(fa.z); v[3]=f2s(fa.w);
        v[4]=f2s(fb.x); v[5]=f2s(fb.y); v[6]=f2s(fb.z); v[7]=f2s(fb.w);
      } else { v = short8v{0,0,0,0,0,0,0,0}; }
      *(short8v*)&As[r][h * 32 + q * 8] = v;
    }
  }
  // stage B from Wtp (already fragment-ready bf16)
  #pragma unroll
  for (int i = 0; i < 5; ++i){
    int idx = t + i * 256;          // 0..1279 chunks of 8
    int cc = idx >> 3, ko = (idx & 7) * 8;
    *(short8v*)&Bs[cc][ko] = *(const short8v*)(Wp + (size_t)(gc0 + cc) * 64 + ko);
  }
  __syncthreads();

  f32x4 acc[2][10] = {};
  #pragma unroll
  for (int kk = 0; kk < 2; ++kk){
    short8v af0 = *(const short8v*)&As[rw + (lane & 15)][kk * 32 + (lane >> 4) * 8];
    short8v af1 = *(const short8v*)&As[rw + 16 + (lane & 15)][kk * 32 + (lane >> 4) * 8];
    #pragma unroll
    for (int j = 0; j < 10; ++j){
      short8v bfj = *(const short8v*)&Bs[j * 16 + (lane & 15)][kk * 32 + (lane >> 4) * 8];
      acc[0][j] = __builtin_amdgcn_mfma_f32_16x16x32_bf16(af0, bfj, acc[0][j], 0, 0, 0);
      acc[1][j] = __builtin_amdgcn_mfma_f32_16x16x32_bf16(af1, bfj, acc[1][j], 0, 0, 0);
    }
  }

  // epilogue: C/D col=lane&15, row=(lane>>4)*4+reg
  #pragma unroll
  for (int i = 0; i < 2; ++i){
    #pragma unroll
    for (int r = 0; r < 4; ++r){
      int n = n0 + rw + i * 16 + (lane >> 4) * 4 + r;
      if (n >= NN) continue;
      #pragma unroll
      for (int j = 0; j < 10; ++j){
        int gc = gc0 + j * 16 + (lane & 15);
        AB[(size_t)n * 640 + gc] = f2b(acc[i][j][r] + bias640[gc]);
      }
    }
  }
}

// ---------- h_lin = h0 + h0@Whsum + bsum (base into d_out) ----------
__global__ __launch_bounds__(256) void k_hlin(const float* __restrict__ h0,
                                              const float* __restrict__ whs,
                                              const float* __restrict__ bs,
                                              float* __restrict__ out){
  __shared__ float As[64][65];
  __shared__ float Ws[64][64];
  const int n0 = blockIdx.x * 64;
  const int t  = threadIdx.y * 16 + threadIdx.x;
  #pragma unroll
  for (int i = 0; i < 16; ++i){
    int idx = t + i * 256;
    int r = idx >> 6, k = idx & 63;
    As[r][k] = (n0 + r < NN) ? h0[(size_t)(n0 + r) * 64 + k] : 0.f;
    Ws[r][k] = whs[idx];
  }
  __syncthreads();
  const int tx = threadIdx.x, ty = threadIdx.y;
  float acc[4][4] = {};
  for (int k = 0; k < 64; ++k){
    float a[4];
    #pragma unroll
    for (int i = 0; i < 4; ++i) a[i] = As[ty * 4 + i][k];
    float4 bv = *(const float4*)&Ws[k][tx * 4];
    float b[4] = {bv.x, bv.y, bv.z, bv.w};
    #pragma unroll
    for (int i = 0; i < 4; ++i)
      #pragma unroll
      for (int j = 0; j < 4; ++j)
        acc[i][j] += a[i] * b[j];
  }
  #pragma unroll
  for (int i = 0; i < 4; ++i){
    int n = n0 + ty * 4 + i;
    if (n >= NN) continue;
    #pragma unroll
    for (int j = 0; j < 4; ++j){
      int c = tx * 4 + j;
      out[(size_t)n * 64 + c] = acc[i][j] + h0[(size_t)n * 64 + c] + bs[c];
    }
  }
}

// ---------- fused aggregate + posttrans, all 5 layers, acc across layers ----------
// block = 64 nodes, 4 waves; wave w owns rows w*16..w*16+15 (lane = feature d)
__global__ __launch_bounds__(256) void k_fused(const bf16* __restrict__ AB,
                                               const bf16* __restrict__ ctab,
                                               const bf16* __restrict__ Wt,
                                               const int* __restrict__ rowptr,
                                               const int* __restrict__ ssrc,
                                               const int* __restrict__ scode,
                                               const float* __restrict__ amp,
                                               const float* __restrict__ att,
                                               float* __restrict__ out){
  __shared__ bf16 Ag[64][264];   // 64 rows x 256 agg cols (+8 pad)
  const int t = threadIdx.x, lane = t & 63, wid = t >> 6;
  const int n0 = blockIdx.x * 64;

  f32x4 acc[12] = {};   // 16 rows x 192 cols per wave, accumulated across layers

  for (int l = 0; l < 5; ++l){
    // ---- phase A: aggregate this wave's 16 nodes into Ag ----
    for (int i = 0; i < 16; ++i){
      int n = n0 + wid * 16 + i;
      int r0 = 0, r1 = 0;
      if (n < NN){ r0 = rowptr[n]; r1 = rowptr[n + 1]; }
      float s = 0.f, sq = 0.f, mx = -1e30f, mn = 1e30f;
      for (int j = r0; j < r1; ++j){
        int src = ssrc[j], cd = scode[j];
        float tv = b2f(AB[(size_t)src * 640 + (5 + l) * 64 + lane]) +
                   b2f(ctab[(cd * 5 + l) * 64 + lane]);
        s += tv; sq += tv * tv;
        mx = fmaxf(mx, tv); mn = fminf(mn, tv);
      }
      int d = r1 - r0;
      float degc = (float)((d > 0) ? d : 1);
      float K = (n < NN) ? b2f(AB[(size_t)n * 640 + l * 64 + lane]) : 0.f;
      float mean = ((float)d * K + s) / degc;
      float MX = (d > 0) ? (K + mx) : 0.f;
      float MN = (d > 0) ? (K + mn) : 0.f;
      float mu = s / degc;
      float var = fmaxf(sq / degc - mu * mu, 0.f);
      float sd = sqrtf(var + EPSV);
      int r = wid * 16 + i;
      Ag[r][lane]       = f2b(mean);
      Ag[r][64 + lane]  = f2b(MX);
      Ag[r][128 + lane] = f2b(MN);
      Ag[r][192 + lane] = f2b(sd);
    }
    __syncthreads();

    // ---- phase B: acc += Ag(16x256) @ Wt[l](256x192), B-frags straight from L2 ----
    const short* Wl = (const short*)(Wt + (size_t)l * 192 * 256);
    for (int kt = 0; kt < 8; ++kt){
      short8v af = *(const short8v*)&Ag[wid * 16 + (lane & 15)][kt * 32 + (lane >> 4) * 8];
      #pragma unroll
      for (int j = 0; j < 12; ++j){
        short8v bfj = *(const short8v*)(Wl + (size_t)(j * 16 + (lane & 15)) * 256 +
                                        kt * 32 + (lane >> 4) * 8);
        acc[j] = __builtin_amdgcn_mfma_f32_16x16x32_bf16(af, bfj, acc[j], 0, 0, 0);
      }
    }
    __syncthreads();   // before next layer overwrites Ag
  }

  // ---- epilogue: out += U + amp*V + att*W ----
  #pragma unroll
  for (int r = 0; r < 4; ++r){
    int n = n0 + wid * 16 + (lane >> 4) * 4 + r;
    if (n >= NN) continue;
    float am = amp[n], at = att[n];
    #pragma unroll
    for (int j4 = 0; j4 < 4; ++j4){
      int c = j4 * 16 + (lane & 15);
      float v = acc[j4][r] + am * acc[4 + j4][r] + at * acc[8 + j4][r];
      out[(size_t)n * 64 + c] += v;
    }
  }
}

extern "C" void kernel_launch(void* const* d_in, const int* in_sizes, int n_in,
                              void* d_out, int out_size, void* d_ws, size_t ws_size,
                              hipStream_t stream){
  const int*   x     = (const int*)d_in[0];
  const int*   ei    = (const int*)d_in[1];
  const int*   ea    = (const int*)d_in[2];
  const float* aemb  = (const float*)d_in[3];
  const float* bemb  = (const float*)d_in[4];
  const float* preW  = (const float*)d_in[5];
  const float* preb  = (const float*)d_in[6];
  const float* postW = (const float*)d_in[7];
  const float* postb = (const float*)d_in[8];
  float* out = (float*)d_out;

  char* p = (char*)d_ws;
  auto alloc = [&](size_t bytes) -> char* {
    char* r = p;
    p += (bytes + 255) & ~(size_t)255;
    return r;
  };
  float* h0      = (float*)alloc((size_t)NN * 64 * 4);
  bf16*  AB      = (bf16*) alloc((size_t)NN * 640 * 2);
  int*   deg     = (int*)  alloc((size_t)NN * 4);
  int*   rowptr  = (int*)  alloc((size_t)(NN + 1) * 4);
  int*   cursor  = (int*)  alloc((size_t)NN * 4);
  float* amp     = (float*)alloc((size_t)NN * 4);
  float* att     = (float*)alloc((size_t)NN * 4);
  int*   code    = (int*)  alloc((size_t)NE * 4);
  int*   ssrc    = (int*)  alloc((size_t)NE * 4);
  int*   scode   = (int*)  alloc((size_t)NE * 4);
  bf16*  ctab    = (bf16*) alloc((size_t)512 * 5 * 64 * 2);
  float* whs     = (float*)alloc((size_t)64 * 64 * 4);
  float* bs      = (float*)alloc((size_t)64 * 4);
  int*   part    = (int*)  alloc((size_t)256 * 4);
  bf16*  Wt      = (bf16*) alloc((size_t)5 * 192 * 256 * 2);
  bf16*  Wtp     = (bf16*) alloc((size_t)640 * 64 * 2);
  float* bias640 = (float*)alloc((size_t)640 * 4);
  if ((size_t)(p - (char*)d_ws) > ws_size) return;

  hipMemsetAsync(deg, 0, (size_t)NN * 4, stream);
  hipMemsetAsync(cursor, 0, (size_t)NN * 4, stream);

  k_h0<<<dim3((NN * 64 + 255) / 256), 256, 0, stream>>>(x, aemb, h0);
  k_deg_code<<<dim3((NE + 255) / 256), 256, 0, stream>>>(ei, ea, deg, code);
  int nblk = (NN + 255) / 256;
  k_scan1<<<dim3(nblk), 256, 0, stream>>>(deg, rowptr, part);
  k_scan2<<<dim3(1), 256, 0, stream>>>(part, nblk);
  k_scan3<<<dim3(nblk), 256, 0, stream>>>(rowptr, part, deg, amp, att);
  k_scatter<<<dim3((NE + 255) / 256), 256, 0, stream>>>(ei, code, rowptr, cursor, ssrc, scode);
  k_ctab<<<dim3(512, 5), 64, 0, stream>>>(bemb, preW, ctab);
  k_whsum<<<dim3(16), 256, 0, stream>>>(postW, postb, whs, bs);
  k_wt<<<dim3((5 * 192 * 256 + 255) / 256), 256, 0, stream>>>(postW, Wt);
  k_wtpre<<<dim3((640 * 64 + 255) / 256), 256, 0, stream>>>(preW, preb, Wtp, bias640);
  k_ab_mfma<<<dim3((NN + 127) / 128, 4), 256, 0, stream>>>(h0, Wtp, bias640, AB);
  k_hlin<<<dim3((NN + 63) / 64), dim3(16, 16), 0, stream>>>(h0, whs, bs, out);
  k_fused<<<dim3((NN + 63) / 64), 256, 0, stream>>>(AB, ctab, Wt, rowptr, ssrc, scode,
                                                    amp, att, out);
}

// Round 4
// 443.552 us; speedup vs baseline: 2.5355x; 2.5355x over previous
//
#include <hip/hip_runtime.h>
#include <hip/hip_bf16.h>

#define NN 50000
#define NE 400000
#define AVG_LOG_F 2.1972245773362196f
#define EPSV 1e-5f

typedef __hip_bfloat16 bf16;
typedef __attribute__((ext_vector_type(8))) short short8v;
typedef __attribute__((ext_vector_type(4))) float f32x4;

__device__ __forceinline__ float b2f(bf16 v){ return __bfloat162float(v); }
__device__ __forceinline__ bf16  f2b(float v){ return __float2bfloat16(v); }
__device__ __forceinline__ short f2s(float v){
  bf16 b = __float2bfloat16(v);
  short s; __builtin_memcpy(&s, &b, 2); return s;
}
__device__ __forceinline__ float s2f(short v){
  bf16 b; __builtin_memcpy(&b, &v, 2); return __bfloat162float(b);
}

// ---------- h0[n][d] = sum_c atom_emb[c][x[n][c]][d] ----------
__global__ void k_h0(const int* __restrict__ x, const float* __restrict__ aemb,
                     float* __restrict__ h0){
  int idx = blockIdx.x * 256 + threadIdx.x;
  if (idx >= NN * 64) return;
  int n = idx >> 6, d = idx & 63;
  float acc = 0.f;
  #pragma unroll
  for (int c = 0; c < 9; ++c){
    int a = x[n * 9 + c];
    acc += aemb[(c * 64 + a) * 64 + d];
  }
  h0[idx] = acc;
}

// ---------- degree histogram + bond code ----------
__global__ void k_deg_code(const int* __restrict__ ei, const int* __restrict__ ea,
                           int* __restrict__ deg, int* __restrict__ code){
  int e = blockIdx.x * 256 + threadIdx.x;
  if (e >= NE) return;
  int dst = ei[NE + e];
  atomicAdd(&deg[dst], 1);
  code[e] = ea[e * 3] + 8 * ea[e * 3 + 1] + 64 * ea[e * 3 + 2];
}

// ---------- exclusive scan of deg -> rowptr ----------
__global__ void k_scan1(const int* __restrict__ deg, int* __restrict__ rowptr,
                        int* __restrict__ part){
  __shared__ int s[256];
  int t = threadIdx.x, i = blockIdx.x * 256 + t;
  int v = (i < NN) ? deg[i] : 0;
  s[t] = v; __syncthreads();
  for (int off = 1; off < 256; off <<= 1){
    int xv = (t >= off) ? s[t - off] : 0;
    __syncthreads();
    s[t] += xv;
    __syncthreads();
  }
  if (i < NN) rowptr[i] = s[t] - v;
  if (t == 255) part[blockIdx.x] = s[255];
}

__global__ void k_scan2(int* __restrict__ part, int nblk){
  __shared__ int s[256];
  int t = threadIdx.x;
  int v = (t < nblk) ? part[t] : 0;
  s[t] = v; __syncthreads();
  for (int off = 1; off < 256; off <<= 1){
    int xv = (t >= off) ? s[t - off] : 0;
    __syncthreads();
    s[t] += xv;
    __syncthreads();
  }
  if (t < nblk) part[t] = s[t] - v;
}

__global__ void k_scan3(int* __restrict__ rowptr, const int* __restrict__ part,
                        const int* __restrict__ deg, float* __restrict__ amp,
                        float* __restrict__ att){
  int i = blockIdx.x * 256 + threadIdx.x;
  if (i < NN){
    rowptr[i] += part[blockIdx.x];
    int d = deg[i];
    float ld = logf((float)max(d, 1) + 1.0f);
    amp[i] = ld / AVG_LOG_F;
    att[i] = AVG_LOG_F / ld;
  }
  if (i == 0) rowptr[NN] = NE;
}

// ---------- scatter edges into CSR order ----------
__global__ void k_scatter(const int* __restrict__ ei, const int* __restrict__ code,
                          const int* __restrict__ rowptr, int* __restrict__ cursor,
                          int* __restrict__ ssrc, int* __restrict__ scode){
  int e = blockIdx.x * 256 + threadIdx.x;
  if (e >= NE) return;
  int dst = ei[NE + e];
  int pos = rowptr[dst] + atomicAdd(&cursor[dst], 1);
  ssrc[pos]  = ei[e];
  scode[pos] = code[e];
}

// ---------- ctab[code][l][d] = (sum_c bond_emb[c][attr_c]) @ preW_e[l] ----------
__global__ void k_ctab(const float* __restrict__ bemb, const float* __restrict__ preW,
                       bf16* __restrict__ ctab){
  __shared__ float et[64];
  int cb = blockIdx.x, l = blockIdx.y, t = threadIdx.x;
  int a0 = cb & 7, a1 = (cb >> 3) & 7, a2 = (cb >> 6) & 7;
  et[t] = bemb[(0 * 8 + a0) * 64 + t] + bemb[(1 * 8 + a1) * 64 + t] + bemb[(2 * 8 + a2) * 64 + t];
  __syncthreads();
  float acc = 0.f;
  const float* W = preW + (l * 192 + 128) * 64;
  for (int k = 0; k < 64; ++k) acc += et[k] * W[k * 64 + t];
  ctab[(cb * 5 + l) * 64 + t] = f2b(acc);
}

// ---------- Whsum / bias sums ----------
__global__ void k_whsum(const float* __restrict__ postW, const float* __restrict__ postb,
                        float* __restrict__ whs, float* __restrict__ bs){
  int idx = blockIdx.x * 256 + threadIdx.x;
  if (idx < 4096){
    int k = idx >> 6, d = idx & 63;
    float a = 0.f;
    for (int l = 0; l < 5; ++l) a += postW[(size_t)(l * 832 + 768 + k) * 64 + d];
    whs[idx] = a;
  }
  if (idx < 64){
    float a = 0.f;
    for (int l = 0; l < 5; ++l) a += postb[l * 64 + idx];
    bs[idx] = a;
  }
}

// ---------- Wt[l][cc][k] = postW[l][g*256 + k][c], cc=g*64+c (fragment-ready bf16) ----------
__global__ void k_wt(const float* __restrict__ postW, bf16* __restrict__ Wt){
  int idx = blockIdx.x * 256 + threadIdx.x;
  if (idx >= 5 * 192 * 256) return;
  int l = idx / (192 * 256);
  int rem = idx % (192 * 256);
  int cc = rem >> 8;
  int k  = rem & 255;
  int g = cc >> 6, c = cc & 63;
  Wt[idx] = f2b(postW[((size_t)l * 832 + g * 256 + k) * 64 + c]);
}

// ---------- Wtp[gc][k] = preW block col-transposed (bf16) + bias640 ----------
__global__ void k_wtpre(const float* __restrict__ preW, const float* __restrict__ preb,
                        bf16* __restrict__ Wtp, float* __restrict__ bias640){
  int idx = blockIdx.x * 256 + threadIdx.x;
  if (idx < 640 * 64){
    int gc = idx >> 6, k = idx & 63;
    int s = gc >> 6, c = gc & 63;
    int l = (s < 5) ? s : s - 5;
    int off = (s < 5) ? 0 : 64;
    Wtp[idx] = f2b(preW[(size_t)(l * 192 + off + k) * 64 + c]);
  }
  if (idx < 640){
    int s = idx >> 6, c = idx & 63;
    bias640[idx] = (s < 5) ? preb[s * 64 + c] : 0.f;
  }
}

// ---------- AB = h0[N,64] @ Wcat[64,640] via MFMA; AB[n][s][64] bf16 ----------
__global__ __launch_bounds__(256) void k_ab_mfma(const float* __restrict__ h0,
                                                 const bf16* __restrict__ Wtp,
                                                 const float* __restrict__ bias640,
                                                 bf16* __restrict__ AB){
  __shared__ bf16 As[128][72];
  __shared__ bf16 Bs[160][72];
  const int t = threadIdx.x;
  const int n0 = blockIdx.x * 128;
  const int gc0 = blockIdx.y * 160;
  const int lane = t & 63, wid = t >> 6;
  const int rw = wid * 32;
  const short* Wp = (const short*)Wtp;

  {
    int r = t >> 1, h = t & 1;
    int n = n0 + r;
    #pragma unroll
    for (int q = 0; q < 4; ++q){
      short8v v;
      if (n < NN){
        const float* src = h0 + (size_t)n * 64 + h * 32 + q * 8;
        float4 fa = *(const float4*)src;
        float4 fb = *(const float4*)(src + 4);
        v[0]=f2s(fa.x); v[1]=f2s(fa.y); v[2]=f2s(fa.z); v[3]=f2s(fa.w);
        v[4]=f2s(fb.x); v[5]=f2s(fb.y); v[6]=f2s(fb.z); v[7]=f2s(fb.w);
      } else { v = short8v{0,0,0,0,0,0,0,0}; }
      *(short8v*)&As[r][h * 32 + q * 8] = v;
    }
  }
  #pragma unroll
  for (int i = 0; i < 5; ++i){
    int idx = t + i * 256;
    int cc = idx >> 3, ko = (idx & 7) * 8;
    *(short8v*)&Bs[cc][ko] = *(const short8v*)(Wp + (size_t)(gc0 + cc) * 64 + ko);
  }
  __syncthreads();

  f32x4 acc[2][10] = {};
  #pragma unroll
  for (int kk = 0; kk < 2; ++kk){
    short8v af0 = *(const short8v*)&As[rw + (lane & 15)][kk * 32 + (lane >> 4) * 8];
    short8v af1 = *(const short8v*)&As[rw + 16 + (lane & 15)][kk * 32 + (lane >> 4) * 8];
    #pragma unroll
    for (int j = 0; j < 10; ++j){
      short8v bfj = *(const short8v*)&Bs[j * 16 + (lane & 15)][kk * 32 + (lane >> 4) * 8];
      acc[0][j] = __builtin_amdgcn_mfma_f32_16x16x32_bf16(af0, bfj, acc[0][j], 0, 0, 0);
      acc[1][j] = __builtin_amdgcn_mfma_f32_16x16x32_bf16(af1, bfj, acc[1][j], 0, 0, 0);
    }
  }

  #pragma unroll
  for (int i = 0; i < 2; ++i){
    #pragma unroll
    for (int r = 0; r < 4; ++r){
      int n = n0 + rw + i * 16 + (lane >> 4) * 4 + r;
      if (n >= NN) continue;
      #pragma unroll
      for (int j = 0; j < 10; ++j){
        int gc = gc0 + j * 16 + (lane & 15);
        AB[(size_t)n * 640 + gc] = f2b(acc[i][j][r] + bias640[gc]);
      }
    }
  }
}

// ---------- h_lin = h0 + h0@Whsum + bsum (base into d_out) ----------
__global__ __launch_bounds__(256) void k_hlin(const float* __restrict__ h0,
                                              const float* __restrict__ whs,
                                              const float* __restrict__ bs,
                                              float* __restrict__ out){
  __shared__ float As[64][65];
  __shared__ float Ws[64][64];
  const int n0 = blockIdx.x * 64;
  const int t  = threadIdx.y * 16 + threadIdx.x;
  #pragma unroll
  for (int i = 0; i < 16; ++i){
    int idx = t + i * 256;
    int r = idx >> 6, k = idx & 63;
    As[r][k] = (n0 + r < NN) ? h0[(size_t)(n0 + r) * 64 + k] : 0.f;
    Ws[r][k] = whs[idx];
  }
  __syncthreads();
  const int tx = threadIdx.x, ty = threadIdx.y;
  float acc[4][4] = {};
  for (int k = 0; k < 64; ++k){
    float a[4];
    #pragma unroll
    for (int i = 0; i < 4; ++i) a[i] = As[ty * 4 + i][k];
    float4 bv = *(const float4*)&Ws[k][tx * 4];
    float b[4] = {bv.x, bv.y, bv.z, bv.w};
    #pragma unroll
    for (int i = 0; i < 4; ++i)
      #pragma unroll
      for (int j = 0; j < 4; ++j)
        acc[i][j] += a[i] * b[j];
  }
  #pragma unroll
  for (int i = 0; i < 4; ++i){
    int n = n0 + ty * 4 + i;
    if (n >= NN) continue;
    #pragma unroll
    for (int j = 0; j < 4; ++j){
      int c = tx * 4 + j;
      out[(size_t)n * 64 + c] = acc[i][j] + h0[(size_t)n * 64 + c] + bs[c];
    }
  }
}

// ---------- fused aggregate + posttrans, 16 nodes/block, 5-layer batched gather ----------
// 4 waves: gather = wave w owns rows w*4..w*4+3 (1 node per iter, 4 iters)
// MFMA   = wave w owns col-triple {w*16, 64+w*16, 128+w*16} -> in-register epilogue
__global__ __launch_bounds__(256) void k_fused(const bf16* __restrict__ AB,
                                               const bf16* __restrict__ ctab,
                                               const bf16* __restrict__ Wt,
                                               const int* __restrict__ rowptr,
                                               const int* __restrict__ ssrc,
                                               const int* __restrict__ scode,
                                               const float* __restrict__ amp,
                                               const float* __restrict__ att,
                                               float* __restrict__ out){
  __shared__ short Ag[5][16][264];
  const int t = threadIdx.x, lane = t & 63, wid = t >> 6;
  const int n0 = blockIdx.x * 16;
  const short* ABs = (const short*)AB;
  const short* CTs = (const short*)ctab;

  // ---- gather phase: all 5 layers per edge visit ----
  #pragma unroll
  for (int i = 0; i < 4; ++i){
    int row = wid * 4 + i;
    int n = n0 + row;
    int r0 = 0, r1 = 0;
    if (n < NN){ r0 = rowptr[n]; r1 = rowptr[n + 1]; }
    float s[5]  = {0.f, 0.f, 0.f, 0.f, 0.f};
    float sq[5] = {0.f, 0.f, 0.f, 0.f, 0.f};
    float mx[5], mn[5];
    #pragma unroll
    for (int l = 0; l < 5; ++l){ mx[l] = -1e30f; mn[l] = 1e30f; }
    for (int j = r0; j < r1; ++j){
      int src = ssrc[j], cd = scode[j];
      const short* ab = ABs + (size_t)src * 640 + 320 + lane;
      const short* ct = CTs + (size_t)cd * 320 + lane;
      #pragma unroll
      for (int l = 0; l < 5; ++l){
        float tv = s2f(ab[l * 64]) + s2f(ct[l * 64]);
        s[l] += tv; sq[l] += tv * tv;
        mx[l] = fmaxf(mx[l], tv); mn[l] = fminf(mn[l], tv);
      }
    }
    int d = r1 - r0;
    float degc = (float)((d > 0) ? d : 1);
    #pragma unroll
    for (int l = 0; l < 5; ++l){
      float K = (n < NN) ? s2f(ABs[(size_t)n * 640 + l * 64 + lane]) : 0.f;
      float mean = ((float)d * K + s[l]) / degc;
      float MX = (d > 0) ? (K + mx[l]) : 0.f;
      float MN = (d > 0) ? (K + mn[l]) : 0.f;
      float mu = s[l] / degc;
      float var = fmaxf(sq[l] / degc - mu * mu, 0.f);
      float sd = sqrtf(var + EPSV);
      Ag[l][row][lane]       = f2s(mean);
      Ag[l][row][64 + lane]  = f2s(MX);
      Ag[l][row][128 + lane] = f2s(MN);
      Ag[l][row][192 + lane] = f2s(sd);
    }
  }
  __syncthreads();

  // ---- MFMA phase: acc[g] covers cols g*64 + wid*16 + (lane&15), rows 0..15 ----
  f32x4 acc[3] = {};
  for (int l = 0; l < 5; ++l){
    const short* Wl = (const short*)Wt + (size_t)l * 192 * 256;
    #pragma unroll
    for (int kt = 0; kt < 8; ++kt){
      short8v af = *(const short8v*)&Ag[l][lane & 15][kt * 32 + (lane >> 4) * 8];
      #pragma unroll
      for (int g = 0; g < 3; ++g){
        const short* bp = Wl + (size_t)(g * 64 + wid * 16 + (lane & 15)) * 256 +
                          kt * 32 + (lane >> 4) * 8;
        short8v bfv = *(const short8v*)bp;
        acc[g] = __builtin_amdgcn_mfma_f32_16x16x32_bf16(af, bfv, acc[g], 0, 0, 0);
      }
    }
  }

  // ---- in-register epilogue: out += U + amp*V + att*W ----
  #pragma unroll
  for (int r = 0; r < 4; ++r){
    int row = (lane >> 4) * 4 + r;
    int n = n0 + row;
    if (n >= NN) continue;
    float am = amp[n], at = att[n];
    int c = wid * 16 + (lane & 15);
    out[(size_t)n * 64 + c] += acc[0][r] + am * acc[1][r] + at * acc[2][r];
  }
}

extern "C" void kernel_launch(void* const* d_in, const int* in_sizes, int n_in,
                              void* d_out, int out_size, void* d_ws, size_t ws_size,
                              hipStream_t stream){
  const int*   x     = (const int*)d_in[0];
  const int*   ei    = (const int*)d_in[1];
  const int*   ea    = (const int*)d_in[2];
  const float* aemb  = (const float*)d_in[3];
  const float* bemb  = (const float*)d_in[4];
  const float* preW  = (const float*)d_in[5];
  const float* preb  = (const float*)d_in[6];
  const float* postW = (const float*)d_in[7];
  const float* postb = (const float*)d_in[8];
  float* out = (float*)d_out;

  char* p = (char*)d_ws;
  auto alloc = [&](size_t bytes) -> char* {
    char* r = p;
    p += (bytes + 255) & ~(size_t)255;
    return r;
  };
  float* h0      = (float*)alloc((size_t)NN * 64 * 4);
  bf16*  AB      = (bf16*) alloc((size_t)NN * 640 * 2);
  int*   deg     = (int*)  alloc((size_t)NN * 4);
  int*   rowptr  = (int*)  alloc((size_t)(NN + 1) * 4);
  int*   cursor  = (int*)  alloc((size_t)NN * 4);
  float* amp     = (float*)alloc((size_t)NN * 4);
  float* att     = (float*)alloc((size_t)NN * 4);
  int*   code    = (int*)  alloc((size_t)NE * 4);
  int*   ssrc    = (int*)  alloc((size_t)NE * 4);
  int*   scode   = (int*)  alloc((size_t)NE * 4);
  bf16*  ctab    = (bf16*) alloc((size_t)512 * 5 * 64 * 2);
  float* whs     = (float*)alloc((size_t)64 * 64 * 4);
  float* bs      = (float*)alloc((size_t)64 * 4);
  int*   part    = (int*)  alloc((size_t)256 * 4);
  bf16*  Wt      = (bf16*) alloc((size_t)5 * 192 * 256 * 2);
  bf16*  Wtp     = (bf16*) alloc((size_t)640 * 64 * 2);
  float* bias640 = (float*)alloc((size_t)640 * 4);
  if ((size_t)(p - (char*)d_ws) > ws_size) return;

  hipMemsetAsync(deg, 0, (size_t)NN * 4, stream);
  hipMemsetAsync(cursor, 0, (size_t)NN * 4, stream);

  k_h0<<<dim3((NN * 64 + 255) / 256), 256, 0, stream>>>(x, aemb, h0);
  k_deg_code<<<dim3((NE + 255) / 256), 256, 0, stream>>>(ei, ea, deg, code);
  int nblk = (NN + 255) / 256;
  k_scan1<<<dim3(nblk), 256, 0, stream>>>(deg, rowptr, part);
  k_scan2<<<dim3(1), 256, 0, stream>>>(part, nblk);
  k_scan3<<<dim3(nblk), 256, 0, stream>>>(rowptr, part, deg, amp, att);
  k_scatter<<<dim3((NE + 255) / 256), 256, 0, stream>>>(ei, code, rowptr, cursor, ssrc, scode);
  k_ctab<<<dim3(512, 5), 64, 0, stream>>>(bemb, preW, ctab);
  k_whsum<<<dim3(16), 256, 0, stream>>>(postW, postb, whs, bs);
  k_wt<<<dim3((5 * 192 * 256 + 255) / 256), 256, 0, stream>>>(postW, Wt);
  k_wtpre<<<dim3((640 * 64 + 255) / 256), 256, 0, stream>>>(preW, preb, Wtp, bias640);
  k_ab_mfma<<<dim3((NN + 127) / 128, 4), 256, 0, stream>>>(h0, Wtp, bias640, AB);
  k_hlin<<<dim3((NN + 63) / 64), dim3(16, 16), 0, stream>>>(h0, whs, bs, out);
  k_fused<<<dim3(NN / 16), 256, 0, stream>>>(AB, ctab, Wt, rowptr, ssrc, scode,
                                             amp, att, out);
}

// Round 5
// 381.437 us; speedup vs baseline: 2.9483x; 1.1628x over previous
//
#include <hip/hip_runtime.h>
#include <hip/hip_bf16.h>

#define NN 50000
#define NE 400000
#define AVG_LOG_F 2.1972245773362196f
#define EPSV 1e-5f

typedef __hip_bfloat16 bf16;
typedef __attribute__((ext_vector_type(8))) short short8v;
typedef __attribute__((ext_vector_type(4))) float f32x4;

__device__ __forceinline__ float b2f(bf16 v){ return __bfloat162float(v); }
__device__ __forceinline__ bf16  f2b(float v){ return __float2bfloat16(v); }
__device__ __forceinline__ short f2s(float v){
  bf16 b = __float2bfloat16(v);
  short s; __builtin_memcpy(&s, &b, 2); return s;
}
__device__ __forceinline__ float s2f(short v){
  bf16 b; __builtin_memcpy(&b, &v, 2); return __bfloat162float(b);
}

// ---------- h0[n][d] = sum_c atom_emb[c][x[n][c]][d] ----------
__global__ void k_h0(const int* __restrict__ x, const float* __restrict__ aemb,
                     float* __restrict__ h0){
  int idx = blockIdx.x * 256 + threadIdx.x;
  if (idx >= NN * 64) return;
  int n = idx >> 6, d = idx & 63;
  float acc = 0.f;
  #pragma unroll
  for (int c = 0; c < 9; ++c){
    int a = x[n * 9 + c];
    acc += aemb[(c * 64 + a) * 64 + d];
  }
  h0[idx] = acc;
}

// ---------- degree histogram + bond code ----------
__global__ void k_deg_code(const int* __restrict__ ei, const int* __restrict__ ea,
                           int* __restrict__ deg, int* __restrict__ code){
  int e = blockIdx.x * 256 + threadIdx.x;
  if (e >= NE) return;
  int dst = ei[NE + e];
  atomicAdd(&deg[dst], 1);
  code[e] = ea[e * 3] + 8 * ea[e * 3 + 1] + 64 * ea[e * 3 + 2];
}

// ---------- exclusive scan of deg -> rowptr ----------
__global__ void k_scan1(const int* __restrict__ deg, int* __restrict__ rowptr,
                        int* __restrict__ part){
  __shared__ int s[256];
  int t = threadIdx.x, i = blockIdx.x * 256 + t;
  int v = (i < NN) ? deg[i] : 0;
  s[t] = v; __syncthreads();
  for (int off = 1; off < 256; off <<= 1){
    int xv = (t >= off) ? s[t - off] : 0;
    __syncthreads();
    s[t] += xv;
    __syncthreads();
  }
  if (i < NN) rowptr[i] = s[t] - v;
  if (t == 255) part[blockIdx.x] = s[255];
}

__global__ void k_scan2(int* __restrict__ part, int nblk){
  __shared__ int s[256];
  int t = threadIdx.x;
  int v = (t < nblk) ? part[t] : 0;
  s[t] = v; __syncthreads();
  for (int off = 1; off < 256; off <<= 1){
    int xv = (t >= off) ? s[t - off] : 0;
    __syncthreads();
    s[t] += xv;
    __syncthreads();
  }
  if (t < nblk) part[t] = s[t] - v;
}

__global__ void k_scan3(int* __restrict__ rowptr, const int* __restrict__ part,
                        const int* __restrict__ deg, float* __restrict__ amp,
                        float* __restrict__ att){
  int i = blockIdx.x * 256 + threadIdx.x;
  if (i < NN){
    rowptr[i] += part[blockIdx.x];
    int d = deg[i];
    float ld = logf((float)max(d, 1) + 1.0f);
    amp[i] = ld / AVG_LOG_F;
    att[i] = AVG_LOG_F / ld;
  }
  if (i == 0) rowptr[NN] = NE;
}

// ---------- scatter edges into CSR order, packed (src, code) ----------
__global__ void k_scatter(const int* __restrict__ ei, const int* __restrict__ code,
                          const int* __restrict__ rowptr, int* __restrict__ cursor,
                          int2* __restrict__ sedge){
  int e = blockIdx.x * 256 + threadIdx.x;
  if (e >= NE) return;
  int dst = ei[NE + e];
  int pos = rowptr[dst] + atomicAdd(&cursor[dst], 1);
  int2 v; v.x = ei[e]; v.y = code[e];
  sedge[pos] = v;
}

// ---------- packed C table: CTp[(code*64+d)*8 + l] = (bond emb sum) @ preW_e[l] ----------
__global__ void k_ctab(const float* __restrict__ bemb, const float* __restrict__ preW,
                       bf16* __restrict__ CTp){
  __shared__ float et[64];
  int cb = blockIdx.x, l = blockIdx.y, t = threadIdx.x;
  int a0 = cb & 7, a1 = (cb >> 3) & 7, a2 = (cb >> 6) & 7;
  et[t] = bemb[(0 * 8 + a0) * 64 + t] + bemb[(1 * 8 + a1) * 64 + t] + bemb[(2 * 8 + a2) * 64 + t];
  __syncthreads();
  float acc = 0.f;
  const float* W = preW + (l * 192 + 128) * 64;
  for (int k = 0; k < 64; ++k) acc += et[k] * W[k * 64 + t];
  CTp[((size_t)cb * 64 + t) * 8 + l] = f2b(acc);
}

// ---------- Whsum / bias sums ----------
__global__ void k_whsum(const float* __restrict__ postW, const float* __restrict__ postb,
                        float* __restrict__ whs, float* __restrict__ bs){
  int idx = blockIdx.x * 256 + threadIdx.x;
  if (idx < 4096){
    int k = idx >> 6, d = idx & 63;
    float a = 0.f;
    for (int l = 0; l < 5; ++l) a += postW[(size_t)(l * 832 + 768 + k) * 64 + d];
    whs[idx] = a;
  }
  if (idx < 64){
    float a = 0.f;
    for (int l = 0; l < 5; ++l) a += postb[l * 64 + idx];
    bs[idx] = a;
  }
}

// ---------- Wt[l][cc][k] = postW[l][g*256 + k][c], cc=g*64+c (fragment-ready bf16) ----------
__global__ void k_wt(const float* __restrict__ postW, bf16* __restrict__ Wt){
  int idx = blockIdx.x * 256 + threadIdx.x;
  if (idx >= 5 * 192 * 256) return;
  int l = idx / (192 * 256);
  int rem = idx % (192 * 256);
  int cc = rem >> 8;
  int k  = rem & 255;
  int g = cc >> 6, c = cc & 63;
  Wt[idx] = f2b(postW[((size_t)l * 832 + g * 256 + k) * 64 + c]);
}

// ---------- Wtp832[gc][k] + bias832 ----------
// gc<320: A-part, l=gc>>6, c=gc&63 -> Wdst_l[k][c] (+preb bias)
// gc>=320: q=gc-320, d=q>>3, l=q&7; l<5 -> Wsrc_l[k][d], else 0 (padding)
__global__ void k_wtpre832(const float* __restrict__ preW, const float* __restrict__ preb,
                           bf16* __restrict__ Wtp, float* __restrict__ bias832){
  int idx = blockIdx.x * 256 + threadIdx.x;
  if (idx < 832 * 64){
    int gc = idx >> 6, k = idx & 63;
    float v;
    if (gc < 320){
      int l = gc >> 6, c = gc & 63;
      v = preW[(size_t)(l * 192 + k) * 64 + c];
    } else {
      int q = gc - 320, d = q >> 3, l = q & 7;
      v = (l < 5) ? preW[(size_t)(l * 192 + 64 + k) * 64 + d] : 0.f;
    }
    Wtp[idx] = f2b(v);
  }
  if (idx < 832){
    bias832[idx] = (idx < 320) ? preb[(idx >> 6) * 64 + (idx & 63)] : 0.f;
  }
}

// ---------- ABU = h0[N,64] @ Wtp832[64,832] via MFMA ----------
// ABU[n][0:320] = A-part (K_l at l*64+d); ABU[n][320 + d*8 + l] = B-part packed
// grid (ceil(N/128), 4): 128 rows x 208 cols per block; 4 waves x (32 rows x 208 cols)
__global__ __launch_bounds__(256) void k_ab_mfma(const float* __restrict__ h0,
                                                 const bf16* __restrict__ Wtp,
                                                 const float* __restrict__ bias832,
                                                 bf16* __restrict__ ABU){
  __shared__ bf16 As[128][72];
  __shared__ bf16 Bs[208][72];
  const int t = threadIdx.x;
  const int n0 = blockIdx.x * 128;
  const int gc0 = blockIdx.y * 208;
  const int lane = t & 63, wid = t >> 6;
  const int rw = wid * 32;
  const short* Wp = (const short*)Wtp;

  // stage A: h0 f32 -> bf16
  {
    int r = t >> 1, h = t & 1;
    int n = n0 + r;
    #pragma unroll
    for (int q = 0; q < 4; ++q){
      short8v v;
      if (n < NN){
        const float* src = h0 + (size_t)n * 64 + h * 32 + q * 8;
        float4 fa = *(const float4*)src;
        float4 fb = *(const float4*)(src + 4);
        v[0]=f2s(fa.x); v[1]=f2s(fa.y); v[2]=f2s(fa.z); v[3]=f2s(fa.w);
        v[4]=f2s(fb.x); v[5]=f2s(fb.y); v[6]=f2s(fb.z); v[7]=f2s(fb.w);
      } else { v = short8v{0,0,0,0,0,0,0,0}; }
      *(short8v*)&As[r][h * 32 + q * 8] = v;
    }
  }
  // stage B: 208 cols x 64 k = 1664 short8-groups
  #pragma unroll
  for (int i = 0; i < 7; ++i){
    int idx = t + i * 256;
    if (idx < 1664){
      int cc = idx >> 3, ko = (idx & 7) * 8;
      *(short8v*)&Bs[cc][ko] = *(const short8v*)(Wp + (size_t)(gc0 + cc) * 64 + ko);
    }
  }
  __syncthreads();

  f32x4 acc[2][13] = {};
  #pragma unroll
  for (int kk = 0; kk < 2; ++kk){
    short8v af0 = *(const short8v*)&As[rw + (lane & 15)][kk * 32 + (lane >> 4) * 8];
    short8v af1 = *(const short8v*)&As[rw + 16 + (lane & 15)][kk * 32 + (lane >> 4) * 8];
    #pragma unroll
    for (int j = 0; j < 13; ++j){
      short8v bfj = *(const short8v*)&Bs[j * 16 + (lane & 15)][kk * 32 + (lane >> 4) * 8];
      acc[0][j] = __builtin_amdgcn_mfma_f32_16x16x32_bf16(af0, bfj, acc[0][j], 0, 0, 0);
      acc[1][j] = __builtin_amdgcn_mfma_f32_16x16x32_bf16(af1, bfj, acc[1][j], 0, 0, 0);
    }
  }

  #pragma unroll
  for (int i = 0; i < 2; ++i){
    #pragma unroll
    for (int r = 0; r < 4; ++r){
      int n = n0 + rw + i * 16 + (lane >> 4) * 4 + r;
      if (n >= NN) continue;
      #pragma unroll
      for (int j = 0; j < 13; ++j){
        int gc = gc0 + j * 16 + (lane & 15);
        ABU[(size_t)n * 832 + gc] = f2b(acc[i][j][r] + bias832[gc]);
      }
    }
  }
}

// ---------- h_lin = h0 + h0@Whsum + bsum (base into d_out) ----------
__global__ __launch_bounds__(256) void k_hlin(const float* __restrict__ h0,
                                              const float* __restrict__ whs,
                                              const float* __restrict__ bs,
                                              float* __restrict__ out){
  __shared__ float As[64][65];
  __shared__ float Ws[64][64];
  const int n0 = blockIdx.x * 64;
  const int t  = threadIdx.y * 16 + threadIdx.x;
  #pragma unroll
  for (int i = 0; i < 16; ++i){
    int idx = t + i * 256;
    int r = idx >> 6, k = idx & 63;
    As[r][k] = (n0 + r < NN) ? h0[(size_t)(n0 + r) * 64 + k] : 0.f;
    Ws[r][k] = whs[idx];
  }
  __syncthreads();
  const int tx = threadIdx.x, ty = threadIdx.y;
  float acc[4][4] = {};
  for (int k = 0; k < 64; ++k){
    float a[4];
    #pragma unroll
    for (int i = 0; i < 4; ++i) a[i] = As[ty * 4 + i][k];
    float4 bv = *(const float4*)&Ws[k][tx * 4];
    float b[4] = {bv.x, bv.y, bv.z, bv.w};
    #pragma unroll
    for (int i = 0; i < 4; ++i)
      #pragma unroll
      for (int j = 0; j < 4; ++j)
        acc[i][j] += a[i] * b[j];
  }
  #pragma unroll
  for (int i = 0; i < 4; ++i){
    int n = n0 + ty * 4 + i;
    if (n >= NN) continue;
    #pragma unroll
    for (int j = 0; j < 4; ++j){
      int c = tx * 4 + j;
      out[(size_t)n * 64 + c] = acc[i][j] + h0[(size_t)n * 64 + c] + bs[c];
    }
  }
}

// ---------- fused aggregate + posttrans ----------
// 512 thr (8 waves), 16 nodes/block; gather: wave w -> nodes {w*2, w*2+1}
// MFMA: waves 0-3 layers 0-2, waves 4-7 layers 3-4; cols (wid&3)*16 trio; LDS combine
__global__ __launch_bounds__(512) void k_fused(const bf16* __restrict__ ABU,
                                               const bf16* __restrict__ CTp,
                                               const bf16* __restrict__ Wt,
                                               const int* __restrict__ rowptr,
                                               const int2* __restrict__ sedge,
                                               const float* __restrict__ amp,
                                               const float* __restrict__ att,
                                               float* __restrict__ out){
  __shared__ __align__(16) short ag[5][16][264];
  const int t = threadIdx.x, lane = t & 63, wid = t >> 6;
  const int n0 = blockIdx.x * 16;
  const short* ABUs = (const short*)ABU;
  const short* CTps = (const short*)CTp;

  // ---- gather phase: 2 nodes per wave, all 5 layers per edge, packed 16B loads ----
  #pragma unroll
  for (int i = 0; i < 2; ++i){
    int row = wid * 2 + i;
    int n = n0 + row;                       // NN % 16 == 0, always valid
    int r0 = rowptr[n], r1 = rowptr[n + 1];
    float s[5]  = {0.f, 0.f, 0.f, 0.f, 0.f};
    float sq[5] = {0.f, 0.f, 0.f, 0.f, 0.f};
    float mx[5], mn[5];
    #pragma unroll
    for (int l = 0; l < 5; ++l){ mx[l] = -1e30f; mn[l] = 1e30f; }

    short8v abv = short8v{0,0,0,0,0,0,0,0}, ctv = short8v{0,0,0,0,0,0,0,0};
    if (r0 < r1){
      int2 e0 = sedge[r0];
      abv = *(const short8v*)(ABUs + (size_t)e0.x * 832 + 320 + lane * 8);
      ctv = *(const short8v*)(CTps + (size_t)e0.y * 512 + lane * 8);
    }
    for (int j = r0; j < r1; ++j){
      short8v a = abv, c = ctv;
      if (j + 1 < r1){
        int2 en = sedge[j + 1];
        abv = *(const short8v*)(ABUs + (size_t)en.x * 832 + 320 + lane * 8);
        ctv = *(const short8v*)(CTps + (size_t)en.y * 512 + lane * 8);
      }
      #pragma unroll
      for (int l = 0; l < 5; ++l){
        float tv = s2f(a[l]) + s2f(c[l]);
        s[l] += tv; sq[l] = fmaf(tv, tv, sq[l]);
        mx[l] = fmaxf(mx[l], tv); mn[l] = fminf(mn[l], tv);
      }
    }
    int d = r1 - r0;
    float degc = (float)((d > 0) ? d : 1);
    #pragma unroll
    for (int l = 0; l < 5; ++l){
      float K = s2f(ABUs[(size_t)n * 832 + l * 64 + lane]);   // includes pre_b
      float mean = ((float)d * K + s[l]) / degc;
      float MX = (d > 0) ? (K + mx[l]) : 0.f;
      float MN = (d > 0) ? (K + mn[l]) : 0.f;
      float mu = s[l] / degc;
      float var = fmaxf(sq[l] / degc - mu * mu, 0.f);
      float sd = sqrtf(var + EPSV);
      ag[l][row][lane]       = f2s(mean);
      ag[l][row][64 + lane]  = f2s(MX);
      ag[l][row][128 + lane] = f2s(MN);
      ag[l][row][192 + lane] = f2s(sd);
    }
  }
  __syncthreads();

  // ---- MFMA phase: wave-halves split the layer loop ----
  const int w4 = wid & 3;
  const int lsta = (wid < 4) ? 0 : 3;
  const int lcnt = (wid < 4) ? 3 : 2;
  f32x4 acc[3] = {};
  const short* Wts = (const short*)Wt;
  for (int li = 0; li < lcnt; ++li){
    int l = lsta + li;
    const short* Wl = Wts + (size_t)l * 192 * 256;
    #pragma unroll
    for (int kt = 0; kt < 8; ++kt){
      short8v af = *(const short8v*)&ag[l][lane & 15][kt * 32 + (lane >> 4) * 8];
      #pragma unroll
      for (int g = 0; g < 3; ++g){
        const short* bp = Wl + (size_t)(g * 64 + w4 * 16 + (lane & 15)) * 256 +
                          kt * 32 + (lane >> 4) * 8;
        short8v bfv = *(const short8v*)bp;
        acc[g] = __builtin_amdgcn_mfma_f32_16x16x32_bf16(af, bfv, acc[g], 0, 0, 0);
      }
    }
  }
  __syncthreads();

  // ---- combine wave-halves via LDS overlay on ag ----
  f32x4* red = (f32x4*)&ag[0][0][0];
  if (wid >= 4){
    #pragma unroll
    for (int g = 0; g < 3; ++g)
      red[((wid - 4) * 3 + g) * 64 + lane] = acc[g];
  }
  __syncthreads();
  if (wid < 4){
    #pragma unroll
    for (int g = 0; g < 3; ++g){
      f32x4 o = red[(wid * 3 + g) * 64 + lane];
      acc[g][0] += o[0]; acc[g][1] += o[1]; acc[g][2] += o[2]; acc[g][3] += o[3];
    }
    // ---- epilogue: out += U + amp*V + att*W ----
    #pragma unroll
    for (int r = 0; r < 4; ++r){
      int row = (lane >> 4) * 4 + r;
      int n = n0 + row;
      float am = amp[n], at = att[n];
      int c = wid * 16 + (lane & 15);
      out[(size_t)n * 64 + c] += acc[0][r] + am * acc[1][r] + at * acc[2][r];
    }
  }
}

extern "C" void kernel_launch(void* const* d_in, const int* in_sizes, int n_in,
                              void* d_out, int out_size, void* d_ws, size_t ws_size,
                              hipStream_t stream){
  const int*   x     = (const int*)d_in[0];
  const int*   ei    = (const int*)d_in[1];
  const int*   ea    = (const int*)d_in[2];
  const float* aemb  = (const float*)d_in[3];
  const float* bemb  = (const float*)d_in[4];
  const float* preW  = (const float*)d_in[5];
  const float* preb  = (const float*)d_in[6];
  const float* postW = (const float*)d_in[7];
  const float* postb = (const float*)d_in[8];
  float* out = (float*)d_out;

  char* p = (char*)d_ws;
  auto alloc = [&](size_t bytes) -> char* {
    char* r = p;
    p += (bytes + 255) & ~(size_t)255;
    return r;
  };
  float* h0      = (float*)alloc((size_t)NN * 64 * 4);
  bf16*  ABU     = (bf16*) alloc((size_t)NN * 832 * 2);
  int*   deg     = (int*)  alloc((size_t)NN * 4);
  int*   rowptr  = (int*)  alloc((size_t)(NN + 1) * 4);
  int*   cursor  = (int*)  alloc((size_t)NN * 4);
  float* amp     = (float*)alloc((size_t)NN * 4);
  float* att     = (float*)alloc((size_t)NN * 4);
  int*   code    = (int*)  alloc((size_t)NE * 4);
  int2*  sedge   = (int2*) alloc((size_t)NE * 8);
  bf16*  CTp     = (bf16*) alloc((size_t)512 * 64 * 8 * 2);
  float* whs     = (float*)alloc((size_t)64 * 64 * 4);
  float* bs      = (float*)alloc((size_t)64 * 4);
  int*   part    = (int*)  alloc((size_t)256 * 4);
  bf16*  Wt      = (bf16*) alloc((size_t)5 * 192 * 256 * 2);
  bf16*  Wtp     = (bf16*) alloc((size_t)832 * 64 * 2);
  float* bias832 = (float*)alloc((size_t)832 * 4);
  if ((size_t)(p - (char*)d_ws) > ws_size) return;

  hipMemsetAsync(deg, 0, (size_t)NN * 4, stream);
  hipMemsetAsync(cursor, 0, (size_t)NN * 4, stream);

  k_h0<<<dim3((NN * 64 + 255) / 256), 256, 0, stream>>>(x, aemb, h0);
  k_deg_code<<<dim3((NE + 255) / 256), 256, 0, stream>>>(ei, ea, deg, code);
  int nblk = (NN + 255) / 256;
  k_scan1<<<dim3(nblk), 256, 0, stream>>>(deg, rowptr, part);
  k_scan2<<<dim3(1), 256, 0, stream>>>(part, nblk);
  k_scan3<<<dim3(nblk), 256, 0, stream>>>(rowptr, part, deg, amp, att);
  k_scatter<<<dim3((NE + 255) / 256), 256, 0, stream>>>(ei, code, rowptr, cursor, sedge);
  k_ctab<<<dim3(512, 5), 64, 0, stream>>>(bemb, preW, CTp);
  k_whsum<<<dim3(16), 256, 0, stream>>>(postW, postb, whs, bs);
  k_wt<<<dim3((5 * 192 * 256 + 255) / 256), 256, 0, stream>>>(postW, Wt);
  k_wtpre832<<<dim3((832 * 64 + 255) / 256), 256, 0, stream>>>(preW, preb, Wtp, bias832);
  k_ab_mfma<<<dim3((NN + 127) / 128, 4), 256, 0, stream>>>(h0, Wtp, bias832, ABU);
  k_hlin<<<dim3((NN + 63) / 64), dim3(16, 16), 0, stream>>>(h0, whs, bs, out);
  k_fused<<<dim3(NN / 16), 512, 0, stream>>>(ABU, CTp, Wt, rowptr, sedge,
                                             amp, att, out);
}